// Round 2
// baseline (79.398 us; speedup 1.0000x reference)
//
#include <hip/hip_runtime.h>

#define Bn 32
#define Nn 256
#define Hn 128
#define En 16
#define WWC (Hn + En)   // 144

typedef float v4 __attribute__((ext_vector_type(4)));

// ================= P1: gate rows + U transpose + P colsum =================
// grid 352 x 256 threads
__global__ __launch_bounds__(256) void k_prep1(const int* __restrict__ adj, const float* __restrict__ U_w,
                                               const float* __restrict__ h,
                                               float* __restrict__ gate, float* __restrict__ U_T,
                                               float* __restrict__ P) {
    int bid = blockIdx.x, t = threadIdx.x;
    if (bid < Nn) {                       // gate[i][j] = (sum_b adj) > 0
        int i = bid, j = t;
        int s = 0;
        #pragma unroll
        for (int b = 0; b < Bn; ++b) s += adj[(b * Nn + i) * Nn + j];
        gate[i * Nn + j] = (s > 0) ? 1.0f : 0.0f;
    } else if (bid < Nn + 64) {           // U_T[m][o] = U_w[o][m]
        int m = (bid - Nn) * 2 + (t >> 7), o = t & 127;
        U_T[m * Hn + o] = U_w[o * Hn + m];
    } else {                              // P[b][h] = sum_i h[b,i,h]
        int b = bid - (Nn + 64);
        __shared__ float red[256];
        int hh = t & 127, half = t >> 7;
        float s = 0.f;
        for (int i = half * 128; i < half * 128 + 128; ++i)
            s += h[((size_t)b * Nn + i) * Hn + hh];
        red[t] = s;
        __syncthreads();
        if (t < 128) P[b * Hn + t] = red[t] + red[t + 128];
    }
}

// ================= P2: count/zlist + fold(A_T,Bm_T,cvec) + Q =================
// grid 433 x 256 threads
__global__ __launch_bounds__(256) void k_prep2(const float* __restrict__ gate, const float* __restrict__ W_w,
                                               const float* __restrict__ W_b, const float* __restrict__ U_T,
                                               const float* __restrict__ P,
                                               float* __restrict__ count, int* __restrict__ zcnt,
                                               int* __restrict__ zlist, float* __restrict__ A_T,
                                               float* __restrict__ Bm_T, float* __restrict__ cvec,
                                               float* __restrict__ Q) {
    int bid = blockIdx.x, t = threadIdx.x;
    if (bid < Nn) {                       // column j stats
        int j = bid;
        bool z = (gate[t * Nn + j] == 0.0f);
        unsigned long long m = __ballot(z);
        int lane = t & 63, w = t >> 6;
        __shared__ int wc[4];
        if (lane == 0) wc[w] = (int)__popcll(m);
        __syncthreads();
        int off = 0;
        for (int q = 0; q < w; ++q) off += wc[q];
        if (z) zlist[j * Nn + off + (int)__popcll(m & ((1ull << lane) - 1ull))] = t;
        if (t == 0) {
            int tot = wc[0] + wc[1] + wc[2] + wc[3];
            zcnt[j] = tot;
            count[j] = (float)(Nn - tot);
        }
    } else if (bid < Nn + 145) {          // fold: A_T / Bm_T / cvec
        int r = bid - Nn;
        if (t < 128) {
            int o = t;
            float s = 0.f;
            if (r < Hn) {
                #pragma unroll 8
                for (int m = 0; m < Hn; ++m) s += U_T[m * Hn + o] * W_w[m * WWC + r];
                A_T[r * Hn + o] = s;
            } else if (r < Hn + En) {
                int e = r - Hn;
                #pragma unroll 8
                for (int m = 0; m < Hn; ++m) s += U_T[m * Hn + o] * W_w[m * WWC + Hn + e];
                Bm_T[e * Hn + o] = s;
            } else {
                #pragma unroll 8
                for (int m = 0; m < Hn; ++m) s += U_T[m * Hn + o] * W_b[m];
                cvec[o] = s;
            }
        }
    } else {                              // Q[b][m] = sum_h Wh[m,h]*P[b,h]
        int b = bid - (Nn + 145);
        if (t < 128) {
            int m = t;
            float s = 0.f;
            #pragma unroll 8
            for (int hh = 0; hh < Hn; ++hh) s += W_w[m * WWC + hh] * P[b * Hn + hh];
            Q[b * Hn + m] = s;
        }
    }
}

// ================= F: fused e_sum streaming + final GEMV =================
// grid (Nn/32, Bn), 512 threads. One block: batch b, 32 columns j0..j0+31.
__global__ __launch_bounds__(512) void k_fused(
    const float* __restrict__ edge, const float* __restrict__ gate, const float* __restrict__ h,
    const float* __restrict__ U_T, const float* __restrict__ U_b, const float* __restrict__ Q,
    const float* __restrict__ cvec, const float* __restrict__ Bm_T, const float* __restrict__ count,
    const int* __restrict__ zcnt, const int* __restrict__ zlist, const float* __restrict__ A_T,
    const int* __restrict__ num_nodes, float* __restrict__ out) {
    int j0 = blockIdx.x * 32, b = blockIdx.y, t = threadIdx.x;
    __shared__ float sg[Nn][32];      // gate tile (32 KB)
    __shared__ float shj[Hn][33];     // h tile transposed, padded (16.9 KB)
    __shared__ float sbm[En][Hn];     // Bm_T (8 KB)
    __shared__ v4 sr[4][128];         // partial e_sum (8 KB)
    __shared__ float ses[32][En];     // e_sum tile (2 KB)
    __shared__ float sq[Hn], sc[Hn], sub[Hn], scnt[32];

    // ---- stage gate tile: 2048 v4 loads ----
    #pragma unroll
    for (int q = 0; q < 4; ++q) {
        int f = t + 512 * q;
        int i = f >> 3, c = f & 7;
        *reinterpret_cast<v4*>(&sg[i][c * 4]) =
            *reinterpret_cast<const v4*>(&gate[i * Nn + j0 + c * 4]);
    }
    // ---- stage h tile (transposed) ----
    #pragma unroll
    for (int q = 0; q < 2; ++q) {
        int f = t + 512 * q;
        int j = f >> 5, c = f & 31;
        v4 v = *reinterpret_cast<const v4*>(&h[((size_t)b * Nn + j0 + j) * Hn + c * 4]);
        shj[c * 4 + 0][j] = v[0];
        shj[c * 4 + 1][j] = v[1];
        shj[c * 4 + 2][j] = v[2];
        shj[c * 4 + 3][j] = v[3];
    }
    {   // Bm_T
        int e = t >> 5, c = t & 31;
        *reinterpret_cast<v4*>(&sbm[e][c * 4]) = *reinterpret_cast<const v4*>(&Bm_T[e * Hn + c * 4]);
    }
    if (t < 32) {
        *reinterpret_cast<v4*>(&sq[t * 4])  = *reinterpret_cast<const v4*>(&Q[b * Hn + t * 4]);
        *reinterpret_cast<v4*>(&sc[t * 4])  = *reinterpret_cast<const v4*>(&cvec[t * 4]);
        *reinterpret_cast<v4*>(&sub[t * 4]) = *reinterpret_cast<const v4*>(&U_b[t * 4]);
        scnt[t] = count[j0 + t];
    }
    __syncthreads();

    // ---- stream edge[b, :, j0..j0+31, :] : 512 KB per block ----
    int ig = t >> 7, s = t & 127, jj = s >> 2, e4 = (s & 3) * 4;
    v4 acc = {0.f, 0.f, 0.f, 0.f};
    const float* bp = edge + ((size_t)b * Nn * Nn + (size_t)(j0 + jj)) * En + e4;
    #pragma unroll 4
    for (int i = ig; i < Nn; i += 4) {
        acc += sg[i][jj] * *reinterpret_cast<const v4*>(bp + (size_t)i * (Nn * En));
    }
    sr[ig][s] = acc;
    __syncthreads();
    if (t < 128) {
        v4 tot = sr[0][t] + sr[1][t] + sr[2][t] + sr[3][t];
        *reinterpret_cast<v4*>(&ses[t >> 2][(t & 3) * 4]) = tot;
    }
    __syncthreads();

    // ---- final GEMV: out[b,j,o] = h[b,j]·U_T[:,o] + U_b + mask*(baseA + e·Bm + count*c - corr) ----
    int og = t & 31, o4 = og * 4, jq = t >> 5, j2 = jq * 2;
    v4 acc0 = {0.f, 0.f, 0.f, 0.f}, acc1 = {0.f, 0.f, 0.f, 0.f}, accb = {0.f, 0.f, 0.f, 0.f};
    #pragma unroll 8
    for (int m = 0; m < Hn; ++m) {
        v4 u = *reinterpret_cast<const v4*>(&U_T[m * Hn + o4]);
        float q = sq[m];
        acc0 += shj[m][j2] * u;
        acc1 += shj[m][j2 + 1] * u;
        accb += q * u;
    }
    int nn = num_nodes[b];
    v4 sub4 = *reinterpret_cast<v4*>(&sub[o4]);
    v4 sc4  = *reinterpret_cast<v4*>(&sc[o4]);
    #pragma unroll
    for (int jh = 0; jh < 2; ++jh) {
        int j = j0 + j2 + jh;
        v4 msg = accb;
        #pragma unroll
        for (int e = 0; e < En; ++e)
            msg += ses[j2 + jh][e] * *reinterpret_cast<v4*>(&sbm[e][o4]);
        msg += scnt[j2 + jh] * sc4;
        int zc = zcnt[j];
        if (zc > 0) {  // exact sparse correction (essentially never taken)
            v4 corr = {0.f, 0.f, 0.f, 0.f};
            for (int z = 0; z < zc; ++z) {
                int i = zlist[j * Nn + z];
                for (int hh = 0; hh < Hn; ++hh)
                    corr += h[((size_t)b * Nn + i) * Hn + hh] *
                            *reinterpret_cast<const v4*>(&A_T[hh * Hn + o4]);
            }
            msg -= corr;
        }
        float maskv = (j < nn) ? 1.0f : 0.0f;
        v4 res = (jh ? acc1 : acc0) + sub4 + maskv * msg;
        *reinterpret_cast<v4*>(&out[((size_t)b * Nn + j) * Hn + o4]) = res;
    }
}

extern "C" void kernel_launch(void* const* d_in, const int* in_sizes, int n_in,
                              void* d_out, int out_size, void* d_ws, size_t ws_size,
                              hipStream_t stream) {
    const float* h    = (const float*)d_in[0];
    const float* edge = (const float*)d_in[1];
    const int*   adj  = (const int*)d_in[2];
    const int*   nn   = (const int*)d_in[3];
    const float* W_w  = (const float*)d_in[4];
    const float* W_b  = (const float*)d_in[5];
    const float* U_w  = (const float*)d_in[6];
    const float* U_b  = (const float*)d_in[7];
    float* out = (float*)d_out;

    float* ws    = (float*)d_ws;
    float* gate  = ws;                 // 65536
    float* count = ws + 65536;         // 256
    int*   zcnt  = (int*)(ws + 65792); // 256
    int*   zlist = (int*)(ws + 66048); // 65536
    float* P     = ws + 131584;        // 4096
    float* U_T   = ws + 135680;        // 16384
    float* A_T   = ws + 152064;        // 16384
    float* Bm_T  = ws + 168448;        // 2048
    float* cvec  = ws + 170496;        // 128
    float* Q     = ws + 170624;        // 4096

    hipLaunchKernelGGL(k_prep1, dim3(Nn + 64 + Bn),  dim3(256), 0, stream, adj, U_w, h, gate, U_T, P);
    hipLaunchKernelGGL(k_prep2, dim3(Nn + 145 + Bn), dim3(256), 0, stream,
                       gate, W_w, W_b, U_T, P, count, zcnt, zlist, A_T, Bm_T, cvec, Q);
    hipLaunchKernelGGL(k_fused, dim3(Nn / 32, Bn),   dim3(512), 0, stream,
                       edge, gate, h, U_T, U_b, Q, cvec, Bm_T, count, zcnt, zlist, A_T, nn, out);
}